// Round 11
// baseline (369.241 us; speedup 1.0000x reference)
//
#include <hip/hip_runtime.h>
#include <hip/hip_bf16.h>
#include <hip/hip_cooperative_groups.h>
#include <stdint.h>

namespace cg = cooperative_groups;

#define NN 100000
#define NE 1600000
#define NF 128
#define B_BKT 1563                  // 64-node buckets == gemm row tiles
#define NB2 256                     // front-end blocks (1/CU, cooperative)
#define EPB (NE / NB2)              // 6250 edges per block (exact)
#define BPB ((B_BKT + NB2 - 1) / NB2)   // 7 scan-buckets per block
#define CONV4 (NN * NF / 4)         // 3.2M float4 groups for convert
#define CAP 3072                    // LDS edge buffer (avg 1024)

typedef __attribute__((ext_vector_type(8))) __bf16 bf16x8;
typedef __attribute__((ext_vector_type(4))) float floatx4;
typedef __attribute__((ext_vector_type(4))) unsigned short ushortx4;
typedef __attribute__((ext_vector_type(8))) unsigned short ushortx8;

static __device__ __forceinline__ unsigned short f2bf(float x) {
    union { float f; unsigned u; } v; v.f = x;
    unsigned r = v.u + 0x7fffu + ((v.u >> 16) & 1u);   // RNE
    return (unsigned short)(r >> 16);
}
static __device__ __forceinline__ float bflo(unsigned w) {
    union { unsigned u; float f; } v; v.u = w << 16; return v.f;
}
static __device__ __forceinline__ float bfhi(unsigned w) {
    union { unsigned u; float f; } v; v.u = w & 0xffff0000u; return v.f;
}

// ONE cooperative front-end kernel replacing setup+scan_a+scan_b+binscatter
// (5 launches -> 2 for the whole pipeline; deletes 3 inter-kernel gaps).
//  phase A: per-block histogram of dst into 1563 buckets; W2t prep (blocks
//           0..7); grid-stride fp32->bf16 convert of feat.
//  sync
//  phase B: per-bucket exclusive scan of the 256 per-block counts (wave-scan,
//           each block owns 7 buckets); bucket totals -> T.
//  sync
//  phase C: every block scans T[1563] in LDS (redundant, cheap) -> absolute
//           bucket offsets O; block 0 publishes offs[] for k_agggemm; cursors
//           cur[i] = O[i] + inBucketPrefix(i, blk); deterministic scatter of
//           packed edges into the bucket-sorted stream (same order semantics
//           as the old k_binscatter -> bit-identical downstream).
__global__ void k_front(const float* __restrict__ feat, unsigned short* __restrict__ featb,
                        const float* __restrict__ wv, const float* __restrict__ wu,
                        unsigned short* __restrict__ w2t,
                        const int* __restrict__ src, const int* __restrict__ dst,
                        int* __restrict__ counts, int* __restrict__ T,
                        int* __restrict__ offs, unsigned* __restrict__ streams) {
    __shared__ int sh[B_BKT + 1];   // hist -> O -> cursors
    __shared__ int part[512];
    int blk = blockIdx.x, tid = threadIdx.x;
    int lane = tid & 63, wave = tid >> 6;

    // ---- phase A ----
    for (int i = tid; i < B_BKT; i += 512) sh[i] = 0;
    __syncthreads();
    {
        int base = blk * EPB, end = base + EPB;
        for (int i = base + tid; i < end; i += 512)
            atomicAdd(&sh[__builtin_nontemporal_load(&dst[i]) >> 6], 1);
    }
    __syncthreads();
    for (int i = tid; i < B_BKT; i += 512)
        counts[i * NB2 + blk] = sh[i];
    if (blk < 8) {                       // W2t prep: ids 0..4095
        int id = blk * 512 + tid;
        int n = id >> 5, kg = id & 31;
        const float* srcm = (kg < 16) ? wv : wu;
        int k0 = (kg & 15) * 8;
        ushortx8 o;
#pragma unroll
        for (int j = 0; j < 8; ++j)
            o[j] = f2bf(srcm[(k0 + j) * 128 + n]);
        *(ushortx8*)(w2t + (n * 32 + (kg ^ (n & 7))) * 8) = o;
    }
    for (int i = blk * 512 + tid; i < CONV4; i += NB2 * 512) {
        floatx4 f = __builtin_nontemporal_load((const floatx4*)feat + i);
        ushortx4 o;
        o.x = f2bf(f.x); o.y = f2bf(f.y); o.z = f2bf(f.z); o.w = f2bf(f.w);
        __builtin_nontemporal_store(o, (ushortx4*)featb + i);
    }
    cg::this_grid().sync();

    // ---- phase B: per-bucket scan over the 256 block-counts ----
    {
        int b0 = blk * BPB;
        for (int bb = wave; bb < BPB; bb += 8) {
            int b = b0 + bb;
            if (b < B_BKT) {
                int* col = counts + b * NB2;
                int run = 0;
#pragma unroll
                for (int sg = 0; sg < 4; ++sg) {
                    int v = col[sg * 64 + lane];
                    int x = v;
#pragma unroll
                    for (int off = 1; off < 64; off <<= 1) {
                        int y = __shfl_up(x, off, 64);
                        if (lane >= off) x += y;
                    }
                    col[sg * 64 + lane] = run + x - v;   // exclusive in-bucket
                    run += __shfl(x, 63, 64);
                }
                if (lane == 0) T[b] = run;
            }
        }
    }
    cg::this_grid().sync();

    // ---- phase C: scan T in LDS, cursors, scatter ----
    for (int i = tid; i < B_BKT; i += 512) sh[i] = T[i];
    __syncthreads();
    {
        int base4 = tid * 4;            // 2048 slots cover 1563
        int v0 = 0, v1 = 0, v2 = 0, v3 = 0;
        if (base4 + 0 < B_BKT) v0 = sh[base4 + 0];
        if (base4 + 1 < B_BKT) v1 = sh[base4 + 1];
        if (base4 + 2 < B_BKT) v2 = sh[base4 + 2];
        if (base4 + 3 < B_BKT) v3 = sh[base4 + 3];
        int tsum = v0 + v1 + v2 + v3;
        part[tid] = tsum;
        __syncthreads();
        for (int off = 1; off < 512; off <<= 1) {
            int u = (tid >= off) ? part[tid - off] : 0;
            __syncthreads();
            part[tid] += u;
            __syncthreads();
        }
        int excl = part[tid] - tsum;
        if (base4 + 0 < B_BKT) sh[base4 + 0] = excl;
        if (base4 + 1 < B_BKT) sh[base4 + 1] = excl + v0;
        if (base4 + 2 < B_BKT) sh[base4 + 2] = excl + v0 + v1;
        if (base4 + 3 < B_BKT) sh[base4 + 3] = excl + v0 + v1 + v2;
    }
    __syncthreads();
    for (int i = tid; i < B_BKT; i += 512) {
        int O = sh[i];
        if (blk == 0) offs[i] = O;                 // publish for k_agggemm
        sh[i] = O + counts[i * NB2 + blk];         // absolute cursor
    }
    if (blk == 0 && tid == 0) offs[B_BKT] = NE;
    __syncthreads();
    {
        int base = blk * EPB, end = base + EPB;
        for (int i = base + tid; i < end; i += 512) {
            int d = __builtin_nontemporal_load(&dst[i]);
            int s = __builtin_nontemporal_load(&src[i]);
            unsigned packed = ((unsigned)(d & 63) << 17) | (unsigned)s;
            int pos = atomicAdd(&sh[d >> 6], 1);
            streams[pos] = packed;
        }
    }
}

// Fully fused CSR-finalize + aggregate + GEMM, 512 threads (8 waves) per
// 64-node bucket (R10 structure, unchanged except segment bounds from offs).
__global__ __launch_bounds__(512, 8) void k_agggemm(
    const unsigned* __restrict__ streams,
    const int* __restrict__ offs,
    const unsigned short* __restrict__ featb,
    const unsigned short* __restrict__ w2t,
    const float* __restrict__ bias,
    float* __restrict__ out) {
    __shared__ int hist[64];
    __shared__ int nodeoff[65];
    __shared__ int eb[CAP];
    __shared__ unsigned short aggt[64 * NF];   // 16 KiB, XOR-swizzled rows
    __shared__ int nextn;
    int tid = threadIdx.x;
    int bkt = blockIdx.x;
    int s = offs[bkt];
    int e = offs[bkt + 1];
    int seg = e - s;
    int lane = tid & 63, wave = tid >> 6;      // wave 0..7

    if (tid < 64) hist[tid] = 0;
    if (tid == 0) nextn = 0;
    __syncthreads();
    for (int i = s + tid; i < e; i += 512)
        atomicAdd(&hist[streams[i] >> 17], 1);
    __syncthreads();
    if (tid == 0) {
        int run = 0;
#pragma unroll
        for (int n = 0; n < 64; ++n) { nodeoff[n] = run; run += hist[n]; }
        nodeoff[64] = run;
    }
    __syncthreads();
    if (tid < 64) hist[tid] = nodeoff[tid];      // reuse as cursor
    __syncthreads();

    if (seg <= CAP) {
        for (int i = s + tid; i < e; i += 512) { // L2-hot second read
            unsigned v = streams[i];
            int p = atomicAdd(&hist[v >> 17], 1);
            eb[p] = (int)(v & 0x1FFFFu);
        }
        __syncthreads();
        for (;;) {                               // dynamic node queue, 8 waves
            int nl;
            if (lane == 0) nl = atomicAdd(&nextn, 1);
            nl = __shfl(nl, 0, 64);
            if (nl >= 64) break;
            int node = bkt * 64 + nl;
            if (node >= NN) continue;
            int s0 = nodeoff[nl], s1 = nodeoff[nl + 1];
            float a0 = 0.f, a1 = 0.f;
            for (int base = s0; base < s1; base += 64) {
                int ee = (base + lane < s1) ? eb[base + lane] : 0;
                int m = s1 - base; if (m > 64) m = 64;
                int j = 0;
                for (; j + 8 <= m; j += 8) {            // 8 loads in flight
                    unsigned w0 = *(const unsigned*)(featb + (size_t)__shfl(ee, j + 0, 64) * NF + lane * 2);
                    unsigned w1 = *(const unsigned*)(featb + (size_t)__shfl(ee, j + 1, 64) * NF + lane * 2);
                    unsigned w2 = *(const unsigned*)(featb + (size_t)__shfl(ee, j + 2, 64) * NF + lane * 2);
                    unsigned w3 = *(const unsigned*)(featb + (size_t)__shfl(ee, j + 3, 64) * NF + lane * 2);
                    unsigned w4 = *(const unsigned*)(featb + (size_t)__shfl(ee, j + 4, 64) * NF + lane * 2);
                    unsigned w5 = *(const unsigned*)(featb + (size_t)__shfl(ee, j + 5, 64) * NF + lane * 2);
                    unsigned w6 = *(const unsigned*)(featb + (size_t)__shfl(ee, j + 6, 64) * NF + lane * 2);
                    unsigned w7 = *(const unsigned*)(featb + (size_t)__shfl(ee, j + 7, 64) * NF + lane * 2);
                    a0 += bflo(w0) + bflo(w1) + bflo(w2) + bflo(w3)
                        + bflo(w4) + bflo(w5) + bflo(w6) + bflo(w7);
                    a1 += bfhi(w0) + bfhi(w1) + bfhi(w2) + bfhi(w3)
                        + bfhi(w4) + bfhi(w5) + bfhi(w6) + bfhi(w7);
                }
                for (; j < m; ++j) {
                    int nn = __shfl(ee, j, 64);
                    unsigned w = *(const unsigned*)(featb + (size_t)nn * NF + lane * 2);
                    a0 += bflo(w); a1 += bfhi(w);
                }
            }
            int dg = s1 - s0; if (dg < 1) dg = 1;
            float scale = 1.0f / (float)dg;
            unsigned outw = ((unsigned)f2bf(a1 * scale) << 16) | (unsigned)f2bf(a0 * scale);
            // swizzled LDS write: lane holds feats [2*lane, 2*lane+1]
            *(unsigned*)((char*)aggt + nl * 256 + ((lane * 4) ^ ((nl & 7) << 4))) = outw;
        }
    } else {
        // safety fallback (statistically unreachable: seg~Poisson(1024)):
        for (int nl = wave * 8; nl < wave * 8 + 8; ++nl) {
            int node = bkt * 64 + nl;
            if (node >= NN) break;
            float a0 = 0.f, a1 = 0.f;
            int dg = 0;
            for (int i = s; i < e; ++i) {
                unsigned v = streams[i];
                if ((int)(v >> 17) == nl) {
                    ++dg;
                    unsigned w = *(const unsigned*)(featb + (size_t)(v & 0x1FFFFu) * NF + lane * 2);
                    a0 += bflo(w); a1 += bfhi(w);
                }
            }
            int dc = dg < 1 ? 1 : dg;
            float scale = 1.0f / (float)dc;
            unsigned outw = ((unsigned)f2bf(a1 * scale) << 16) | (unsigned)f2bf(a0 * scale);
            *(unsigned*)((char*)aggt + nl * 256 + ((lane * 4) ^ ((nl & 7) << 4))) = outw;
        }
    }
    __syncthreads();

    // ---- GEMM phase: wave (rg = w&3, ch = w>>2): rows rg*16..+16,
    //      ct = ch*4..+4 (cols ch*64..+64). 32 MFMAs per wave. ----
    int quad = lane >> 4, l15 = lane & 15;
    int rg = wave & 3, ch = wave >> 2;
    int rbl = rg * 16;                   // local row base
    int rb = bkt * 64 + rbl;             // global row base
    int ar = rb + l15; if (ar > NN - 1) ar = NN - 1;
    const unsigned short* fr = featb + (size_t)ar * NF;
    int lrow = rbl + l15;                // local row 0..63
    bf16x8 a[8];
#pragma unroll
    for (int ks = 0; ks < 4; ++ks)       // feat half of A (k = 0..127)
        a[ks] = *(const bf16x8*)(fr + ks * 32 + quad * 8);
#pragma unroll
    for (int ks = 0; ks < 4; ++ks) {     // agg half of A (k = 128..255), LDS
        int boff = (ks * 64 + quad * 16) ^ ((lrow & 7) << 4);
        a[4 + ks] = *(const bf16x8*)((const char*)aggt + lrow * 256 + boff);
    }
    float bsv[4];
#pragma unroll
    for (int c = 0; c < 4; ++c) bsv[c] = bias[(ch * 4 + c) * 16 + l15];
#pragma unroll 2
    for (int c = 0; c < 4; ++c) {        // unroll 2: 16 B-loads in flight
        int ct = ch * 4 + c;
        int n = ct * 16 + l15;
        const unsigned short* wrow = w2t + (n << 8);
        int sw = n & 7;
        floatx4 acc = (floatx4){0.f, 0.f, 0.f, 0.f};
#pragma unroll
        for (int ks = 0; ks < 8; ++ks) {
            int kg = ks * 4 + quad;
            bf16x8 b = *(const bf16x8*)(wrow + ((kg ^ sw) << 3));   // L2-hot
            acc = __builtin_amdgcn_mfma_f32_16x16x32_bf16(a[ks], b, acc, 0, 0, 0);
        }
#pragma unroll
        for (int r = 0; r < 4; ++r) {
            int row = rb + quad * 4 + r;
            if (row < NN) {
                float v = acc[r] + bsv[c];
                out[(size_t)row * NF + ct * 16 + l15] = v > 0.f ? v : 0.f;
            }
        }
    }
}

extern "C" void kernel_launch(void* const* d_in, const int* in_sizes, int n_in,
                              void* d_out, int out_size, void* d_ws, size_t ws_size,
                              hipStream_t stream) {
    const float* feat = (const float*)d_in[0];
    const float* wu   = (const float*)d_in[1];
    const float* wv   = (const float*)d_in[2];
    const float* bias = (const float*)d_in[3];
    const int* src    = (const int*)d_in[4];
    const int* dst    = (const int*)d_in[5];
    float* out        = (float*)d_out;

    char* ws = (char*)d_ws;
    int* counts           = (int*)(ws + 0);                    // 1,600,512 B
    int* T                = (int*)(ws + 1600512);              //     6,256 B
    int* offs             = (int*)(ws + 1606768);              //     6,256 B
    unsigned* streams     = (unsigned*)(ws + 1613024);         // 6,400,000 B
    unsigned short* featb = (unsigned short*)(ws + 8013024);   // 25,600,000 B
    unsigned short* w2t   = (unsigned short*)(ws + 33613024);  //    65,536 B

    void* fargs[] = { (void*)&feat, (void*)&featb, (void*)&wv, (void*)&wu,
                      (void*)&w2t, (void*)&src, (void*)&dst,
                      (void*)&counts, (void*)&T, (void*)&offs, (void*)&streams };
    hipLaunchCooperativeKernel((void*)k_front, dim3(NB2), dim3(512),
                               fargs, 0, stream);
    k_agggemm<<<B_BKT, 512, 0, stream>>>(streams, offs, featb, w2t, bias, out);
}

// Round 12
// 285.215 us; speedup vs baseline: 1.2946x; 1.2946x over previous
//
#include <hip/hip_runtime.h>
#include <hip/hip_bf16.h>
#include <stdint.h>

#define NN 100000
#define NE 1600000
#define NF 128
#define B_BKT 1563                  // 64-node buckets == gemm row tiles
#define NB2 128                     // binning blocks
#define EPB (NE / NB2)              // 12500 edges per binning block
#define NCNT (B_BKT * NB2)          // 200,064 segment counters
#define SC2A ((NCNT + 255) / 256)   // 782 scan blocks
#define CONV4 (NN * NF / 4)         // 3.2M float4 groups for convert
#define CONV_BLK ((CONV4 + 255) / 256)   // 12500
#define SETUP_GRID (NB2 + 16 + CONV_BLK) // count | prep | convert
#define CAP 3072                    // LDS edge buffer (avg 1024); 29KB LDS,
                                    // 4 blocks/CU at 512 thr = 32-wave cap

typedef __attribute__((ext_vector_type(8))) __bf16 bf16x8;
typedef __attribute__((ext_vector_type(4))) float floatx4;
typedef __attribute__((ext_vector_type(4))) unsigned short ushortx4;
typedef __attribute__((ext_vector_type(8))) unsigned short ushortx8;

static __device__ __forceinline__ unsigned short f2bf(float x) {
    union { float f; unsigned u; } v; v.f = x;
    unsigned r = v.u + 0x7fffu + ((v.u >> 16) & 1u);   // RNE
    return (unsigned short)(r >> 16);
}
static __device__ __forceinline__ float bflo(unsigned w) {
    union { unsigned u; float f; } v; v.u = w << 16; return v.f;
}
static __device__ __forceinline__ float bfhi(unsigned w) {
    union { unsigned u; float f; } v; v.u = w & 0xffff0000u; return v.f;
}

// Fused setup: blocks [0,NB2) histogram dst into 1563 fine buckets;
// blocks [NB2,NB2+16) build the swizzled W2t; the rest convert feat->bf16.
__global__ void k_setup(const float* __restrict__ feat, unsigned short* __restrict__ featb,
                        const float* __restrict__ wv, const float* __restrict__ wu,
                        unsigned short* __restrict__ w2t,
                        const int* __restrict__ dst, int* __restrict__ counts) {
    __shared__ int h[B_BKT];
    int b = blockIdx.x;
    int tid = threadIdx.x;
    if (b < NB2) {                       // ---- count ----
        for (int i = tid; i < B_BKT; i += 256) h[i] = 0;
        __syncthreads();
        int base = b * EPB, end = base + EPB;
        for (int i = base + tid; i < end; i += 256) {
            int d = __builtin_nontemporal_load(&dst[i]);
            atomicAdd(&h[d >> 6], 1);
        }
        __syncthreads();
        for (int i = tid; i < B_BKT; i += 256)
            counts[i * NB2 + b] = h[i];
    } else if (b < NB2 + 16) {           // ---- prep W2t ----
        int id = (b - NB2) * 256 + tid;  // 0..4095
        if (id < 128 * 32) {
            int n = id >> 5, kg = id & 31;
            const float* srcm = (kg < 16) ? wv : wu;
            int k0 = (kg & 15) * 8;
            ushortx8 o;
#pragma unroll
            for (int j = 0; j < 8; ++j)
                o[j] = f2bf(srcm[(k0 + j) * 128 + n]);
            int dchunk = n * 32 + (kg ^ (n & 7));
            *(ushortx8*)(w2t + dchunk * 8) = o;
        }
    } else {                             // ---- convert fp32 -> bf16 ----
        int i = (b - NB2 - 16) * 256 + tid;
        if (i < CONV4) {
            floatx4 f = __builtin_nontemporal_load((const floatx4*)feat + i);
            ushortx4 o;
            o.x = f2bf(f.x); o.y = f2bf(f.y); o.z = f2bf(f.z); o.w = f2bf(f.w);
            __builtin_nontemporal_store(o, (ushortx4*)featb + i);
        }
    }
}

// hierarchical exclusive scan of the 200,064 counts (bucket-major).
__global__ void k_scan2_a(int* __restrict__ counts, int* __restrict__ bsums) {
    __shared__ int sh[256];
    int i = blockIdx.x * 256 + threadIdx.x;
    int v = (i < NCNT) ? counts[i] : 0;
    sh[threadIdx.x] = v;
    __syncthreads();
    for (int off = 1; off < 256; off <<= 1) {
        int u = (threadIdx.x >= off) ? sh[threadIdx.x - off] : 0;
        __syncthreads();
        sh[threadIdx.x] += u;
        __syncthreads();
    }
    if (i < NCNT) counts[i] = sh[threadIdx.x] - v;
    if (threadIdx.x == 255) bsums[blockIdx.x] = sh[255];
}
__global__ void k_scan2_b(int* __restrict__ bsums) {
    __shared__ int sh[1024];
    int t = threadIdx.x;
    int v = (t < SC2A) ? bsums[t] : 0;
    sh[t] = v;
    __syncthreads();
    for (int off = 1; off < 1024; off <<= 1) {
        int u = (t >= off) ? sh[t - off] : 0;
        __syncthreads();
        sh[t] += u;
        __syncthreads();
    }
    if (t < SC2A) bsums[t] = sh[t] - v;
}

// pass 2: deterministic scatter into bucket-sorted stream; LDS cursors only.
__global__ void k_binscatter(const int* __restrict__ src, const int* __restrict__ dst,
                             const int* __restrict__ counts, const int* __restrict__ bsums,
                             unsigned* __restrict__ streams) {
    __shared__ int cur[B_BKT];
    int tid = threadIdx.x;
    for (int i = tid; i < B_BKT; i += 512) {
        int idx = i * NB2 + blockIdx.x;
        cur[i] = counts[idx] + bsums[idx >> 8];
    }
    __syncthreads();
    int base = blockIdx.x * EPB, end = base + EPB;
    for (int i = base + tid; i < end; i += 512) {
        int d = __builtin_nontemporal_load(&dst[i]);
        int s = __builtin_nontemporal_load(&src[i]);
        int b = d >> 6;
        unsigned packed = ((unsigned)(d & 63) << 17) | (unsigned)s;
        int pos = atomicAdd(&cur[b], 1);
        streams[pos] = packed;
    }
}

// Fully fused CSR-finalize + aggregate + GEMM, 512 threads (8 waves) per
// 64-node bucket. 8 waves/block doubles gather parallelism per bucket and
// 4 blocks/CU hits the hard 32-wave/CU occupancy cap. LB(512,8) pins
// VGPR<=64 (measured use 32).
//  phase 1: counting-sort the bucket's edge segment into LDS (eb)
//  phase 2: shfl-broadcast gather (dynamic node queue) -> 16KB swizzled aggt
//  phase 3: GEMM; wave w = (rowgroup w&3, colhalf w>>2): 16 rows x 4 ct.
__global__ __launch_bounds__(512, 8) void k_agggemm(
    const unsigned* __restrict__ streams,
    const int* __restrict__ counts, const int* __restrict__ bsums,
    const unsigned short* __restrict__ featb,
    const unsigned short* __restrict__ w2t,
    const float* __restrict__ bias,
    float* __restrict__ out) {
    __shared__ int hist[64];
    __shared__ int nodeoff[65];
    __shared__ int eb[CAP];
    __shared__ unsigned short aggt[64 * NF];   // 16 KiB, XOR-swizzled rows
    __shared__ int nextn;
    int tid = threadIdx.x;
    int bkt = blockIdx.x;
    int idx = bkt * NB2;
    int s = counts[idx] + bsums[idx >> 8];
    int e = (bkt == B_BKT - 1) ? NE : (counts[idx + NB2] + bsums[(idx + NB2) >> 8]);
    int seg = e - s;
    int lane = tid & 63, wave = tid >> 6;      // wave 0..7

    if (tid < 64) hist[tid] = 0;
    if (tid == 0) nextn = 0;
    __syncthreads();
    for (int i = s + tid; i < e; i += 512)
        atomicAdd(&hist[streams[i] >> 17], 1);
    __syncthreads();
    if (tid == 0) {
        int run = 0;
#pragma unroll
        for (int n = 0; n < 64; ++n) { nodeoff[n] = run; run += hist[n]; }
        nodeoff[64] = run;
    }
    __syncthreads();
    if (tid < 64) hist[tid] = nodeoff[tid];      // reuse as cursor
    __syncthreads();

    if (seg <= CAP) {
        for (int i = s + tid; i < e; i += 512) { // L2-hot second read
            unsigned v = streams[i];
            int p = atomicAdd(&hist[v >> 17], 1);
            eb[p] = (int)(v & 0x1FFFFu);
        }
        __syncthreads();
        for (;;) {                               // dynamic node queue, 8 waves
            int nl;
            if (lane == 0) nl = atomicAdd(&nextn, 1);
            nl = __shfl(nl, 0, 64);
            if (nl >= 64) break;
            int node = bkt * 64 + nl;
            if (node >= NN) continue;
            int s0 = nodeoff[nl], s1 = nodeoff[nl + 1];
            float a0 = 0.f, a1 = 0.f;
            for (int base = s0; base < s1; base += 64) {
                int ee = (base + lane < s1) ? eb[base + lane] : 0;
                int m = s1 - base; if (m > 64) m = 64;
                int j = 0;
                for (; j + 8 <= m; j += 8) {            // 8 loads in flight
                    unsigned w0 = *(const unsigned*)(featb + (size_t)__shfl(ee, j + 0, 64) * NF + lane * 2);
                    unsigned w1 = *(const unsigned*)(featb + (size_t)__shfl(ee, j + 1, 64) * NF + lane * 2);
                    unsigned w2 = *(const unsigned*)(featb + (size_t)__shfl(ee, j + 2, 64) * NF + lane * 2);
                    unsigned w3 = *(const unsigned*)(featb + (size_t)__shfl(ee, j + 3, 64) * NF + lane * 2);
                    unsigned w4 = *(const unsigned*)(featb + (size_t)__shfl(ee, j + 4, 64) * NF + lane * 2);
                    unsigned w5 = *(const unsigned*)(featb + (size_t)__shfl(ee, j + 5, 64) * NF + lane * 2);
                    unsigned w6 = *(const unsigned*)(featb + (size_t)__shfl(ee, j + 6, 64) * NF + lane * 2);
                    unsigned w7 = *(const unsigned*)(featb + (size_t)__shfl(ee, j + 7, 64) * NF + lane * 2);
                    a0 += bflo(w0) + bflo(w1) + bflo(w2) + bflo(w3)
                        + bflo(w4) + bflo(w5) + bflo(w6) + bflo(w7);
                    a1 += bfhi(w0) + bfhi(w1) + bfhi(w2) + bfhi(w3)
                        + bfhi(w4) + bfhi(w5) + bfhi(w6) + bfhi(w7);
                }
                for (; j < m; ++j) {
                    int nn = __shfl(ee, j, 64);
                    unsigned w = *(const unsigned*)(featb + (size_t)nn * NF + lane * 2);
                    a0 += bflo(w); a1 += bfhi(w);
                }
            }
            int dg = s1 - s0; if (dg < 1) dg = 1;
            float scale = 1.0f / (float)dg;
            unsigned outw = ((unsigned)f2bf(a1 * scale) << 16) | (unsigned)f2bf(a0 * scale);
            // swizzled LDS write: lane holds feats [2*lane, 2*lane+1]
            *(unsigned*)((char*)aggt + nl * 256 + ((lane * 4) ^ ((nl & 7) << 4))) = outw;
        }
    } else {
        // safety fallback (statistically unreachable: seg~Poisson(1024)):
        for (int nl = wave * 8; nl < wave * 8 + 8; ++nl) {
            int node = bkt * 64 + nl;
            if (node >= NN) break;
            float a0 = 0.f, a1 = 0.f;
            int dg = 0;
            for (int i = s; i < e; ++i) {
                unsigned v = streams[i];
                if ((int)(v >> 17) == nl) {
                    ++dg;
                    unsigned w = *(const unsigned*)(featb + (size_t)(v & 0x1FFFFu) * NF + lane * 2);
                    a0 += bflo(w); a1 += bfhi(w);
                }
            }
            int dc = dg < 1 ? 1 : dg;
            float scale = 1.0f / (float)dc;
            unsigned outw = ((unsigned)f2bf(a1 * scale) << 16) | (unsigned)f2bf(a0 * scale);
            *(unsigned*)((char*)aggt + nl * 256 + ((lane * 4) ^ ((nl & 7) << 4))) = outw;
        }
    }
    __syncthreads();

    // ---- GEMM phase: wave (rg = w&3, ch = w>>2): rows rg*16..+16,
    //      ct = ch*4..+4 (cols ch*64..+64). 32 MFMAs per wave. ----
    int quad = lane >> 4, l15 = lane & 15;
    int rg = wave & 3, ch = wave >> 2;
    int rbl = rg * 16;                   // local row base
    int rb = bkt * 64 + rbl;             // global row base
    int ar = rb + l15; if (ar > NN - 1) ar = NN - 1;
    const unsigned short* fr = featb + (size_t)ar * NF;
    int lrow = rbl + l15;                // local row 0..63
    bf16x8 a[8];
#pragma unroll
    for (int ks = 0; ks < 4; ++ks)       // feat half of A (k = 0..127)
        a[ks] = *(const bf16x8*)(fr + ks * 32 + quad * 8);
#pragma unroll
    for (int ks = 0; ks < 4; ++ks) {     // agg half of A (k = 128..255), LDS
        int boff = (ks * 64 + quad * 16) ^ ((lrow & 7) << 4);
        a[4 + ks] = *(const bf16x8*)((const char*)aggt + lrow * 256 + boff);
    }
    float bsv[4];
#pragma unroll
    for (int c = 0; c < 4; ++c) bsv[c] = bias[(ch * 4 + c) * 16 + l15];
#pragma unroll 2
    for (int c = 0; c < 4; ++c) {        // unroll 2: 16 B-loads in flight
        int ct = ch * 4 + c;
        int n = ct * 16 + l15;
        const unsigned short* wrow = w2t + (n << 8);
        int sw = n & 7;
        floatx4 acc = (floatx4){0.f, 0.f, 0.f, 0.f};
#pragma unroll
        for (int ks = 0; ks < 8; ++ks) {
            int kg = ks * 4 + quad;
            bf16x8 b = *(const bf16x8*)(wrow + ((kg ^ sw) << 3));   // L2-hot
            acc = __builtin_amdgcn_mfma_f32_16x16x32_bf16(a[ks], b, acc, 0, 0, 0);
        }
#pragma unroll
        for (int r = 0; r < 4; ++r) {
            int row = rb + quad * 4 + r;
            if (row < NN) {
                float v = acc[r] + bsv[c];
                out[(size_t)row * NF + ct * 16 + l15] = v > 0.f ? v : 0.f;
            }
        }
    }
}

extern "C" void kernel_launch(void* const* d_in, const int* in_sizes, int n_in,
                              void* d_out, int out_size, void* d_ws, size_t ws_size,
                              hipStream_t stream) {
    const float* feat = (const float*)d_in[0];
    const float* wu   = (const float*)d_in[1];
    const float* wv   = (const float*)d_in[2];
    const float* bias = (const float*)d_in[3];
    const int* src    = (const int*)d_in[4];
    const int* dst    = (const int*)d_in[5];
    float* out        = (float*)d_out;

    char* ws = (char*)d_ws;
    int* counts           = (int*)(ws + 0);                    //   800,256 B
    int* bsums            = (int*)(ws + 800256);               //     4,096 B
    unsigned* streams     = (unsigned*)(ws + 1204480);         // 6,400,000 B
    unsigned short* featb = (unsigned short*)(ws + 7604480);   // 25,600,000 B
    unsigned short* w2t   = (unsigned short*)(ws + 58804480);  //    65,536 B

    k_setup<<<SETUP_GRID, 256, 0, stream>>>(feat, featb, wv, wu, w2t, dst, counts);
    k_scan2_a<<<SC2A, 256, 0, stream>>>(counts, bsums);
    k_scan2_b<<<1, 1024, 0, stream>>>(bsums);
    k_binscatter<<<NB2, 512, 0, stream>>>(src, dst, counts, bsums, streams);
    k_agggemm<<<B_BKT, 512, 0, stream>>>(streams, counts, bsums, featb, w2t, bias, out);
}